// Round 2
// baseline (64563.727 us; speedup 1.0000x reference)
//
#include <hip/hip_runtime.h>
#include <hip/hip_bf16.h>
#include <stdint.h>

#define NS 4096     // samples / time steps
#define DT 1024     // dim_t == hidden == in
#define H4 4096     // 4*HID

// ---------- math helpers ----------
__device__ __forceinline__ float sigm_f(float x) { return 1.f / (1.f + __expf(-x)); }
__device__ __forceinline__ float tanh_f(float x) {
    float ax = fminf(fabsf(x), 15.f);                 // overflow-safe
    float t = 1.f - 2.f / (__expf(2.f * ax) + 1.f);
    return copysignf(t, x);
}

// ---------- sinusoidal embedding ----------
__global__ void emb_kernel(const int* __restrict__ ts, float* __restrict__ emb) {
    int t = blockIdx.x;
    int i = threadIdx.x;                 // 0..511
    float tv = (float)ts[t];
    const float c = -0.018024149455922082f;  // -ln(10000)/511
    float f = __expf(c * (float)i);
    float a = tv * f;
    float s, co;
    sincosf(a, &s, &co);
    emb[(size_t)t * DT + i] = s;
    emb[(size_t)t * DT + 512 + i] = co;
}

// ---------- generic C = A(M,K) @ B(Nc,K)^T + bias [+bias2] [+skip] [silu] ----------
// BM=128, BN=64, BK=16, 256 threads, each thread 8x4 outputs.
// XGMODE: 0 = plain fp32 C; 1 = bf16 XG layout; 2 = fp32 XG layout.
// XG layout per epoch (4096 elems): pos = k*16 + r*4 + q for col = q*1024 + 4k + r.
template <bool SILU, bool SKIP, int XGMODE>
__global__ __launch_bounds__(256) void gemm_bt(
    const float* __restrict__ A, const float* __restrict__ B,
    const float* __restrict__ bias, const float* __restrict__ bias2,
    const float* __restrict__ skip, float* __restrict__ Cf,
    __hip_bfloat16* __restrict__ Cb, int M, int Nc, int K)
{
    __shared__ __align__(16) float As[16][132];
    __shared__ __align__(16) float Bs[16][68];
    const int bn = blockIdx.x, bm = blockIdx.y, lz = blockIdx.z;
    if (XGMODE) {
        B     += (size_t)lz * H4 * DT;
        bias  += (size_t)lz * H4;
        bias2 += (size_t)lz * H4;
    }
    const int tid = threadIdx.x;
    const int tr = tid >> 4, tc = tid & 15;
    const int alr = tid >> 1, alc = (tid & 1) << 3;   // A: 128 rows x 16 cols
    const int blr = tid >> 2, blc = (tid & 3) << 2;   // B: 64 rows x 16 cols
    const float* Ap = A + (size_t)(bm * 128 + alr) * K + alc;
    const float* Bp = B + (size_t)(bn * 64 + blr) * K + blc;

    float acc[8][4];
#pragma unroll
    for (int i = 0; i < 8; i++)
#pragma unroll
        for (int j = 0; j < 4; j++) acc[i][j] = 0.f;

    for (int kk = 0; kk < K; kk += 16) {
        float4 a0 = *(const float4*)(Ap + kk);
        float4 a1 = *(const float4*)(Ap + kk + 4);
        float4 b0 = *(const float4*)(Bp + kk);
        __syncthreads();
        As[alc + 0][alr] = a0.x; As[alc + 1][alr] = a0.y;
        As[alc + 2][alr] = a0.z; As[alc + 3][alr] = a0.w;
        As[alc + 4][alr] = a1.x; As[alc + 5][alr] = a1.y;
        As[alc + 6][alr] = a1.z; As[alc + 7][alr] = a1.w;
        Bs[blc + 0][blr] = b0.x; Bs[blc + 1][blr] = b0.y;
        Bs[blc + 2][blr] = b0.z; Bs[blc + 3][blr] = b0.w;
        __syncthreads();
#pragma unroll
        for (int k = 0; k < 16; k++) {
            const float4 av0 = *(const float4*)&As[k][tr * 8];
            const float4 av1 = *(const float4*)&As[k][tr * 8 + 4];
            const float4 bv  = *(const float4*)&Bs[k][tc * 4];
            float aa[8] = {av0.x, av0.y, av0.z, av0.w, av1.x, av1.y, av1.z, av1.w};
            float bb[4] = {bv.x, bv.y, bv.z, bv.w};
#pragma unroll
            for (int i = 0; i < 8; i++)
#pragma unroll
                for (int j = 0; j < 4; j++)
                    acc[i][j] = fmaf(aa[i], bb[j], acc[i][j]);
        }
    }

#pragma unroll
    for (int i = 0; i < 8; i++) {
        int row = bm * 128 + tr * 8 + i;
#pragma unroll
        for (int j = 0; j < 4; j++) {
            int col = bn * 64 + tc * 4 + j;
            float v = acc[i][j] + bias[col];
            if (XGMODE) v += bias2[col];
            if (SKIP)   v += skip[(size_t)row * Nc + col];
            if (SILU)   v = v * (1.f / (1.f + __expf(-v)));
            if (XGMODE) {
                int q = col >> 10, jj = col & 1023;
                size_t idx = (size_t)row * 16384 + (size_t)lz * 4096
                           + ((size_t)(jj >> 2) << 4) + ((jj & 3) << 2) + q;
                if (XGMODE == 2) Cf[idx] = v;
                else             Cb[idx] = __float2bfloat16(v);
            } else {
                Cf[(size_t)row * Nc + col] = v;
            }
        }
    }
}

// ---------- persistent sequential LSTM chain ----------
// 256 WGs x 256 threads (1 block/CU, co-resident). Wave-owns-row layout:
// wave w of WG k owns hidden row 4k+w and computes ALL 4 gates of that row.
// Poll+stage (proven pattern, 1x fabric traffic): thread t polls words
// {256m+t} of the tagged h buffer and stages to LDS lh[parity] (double-
// buffered by epoch parity). Safety of the parity buffer: staging epoch e+2
// into lh[p] happens only after this thread passed B1 of the iteration that
// produced e+1, and every WG-mate's last read of lh[p] (production of e-1)
// precedes that same barrier -> one barrier per iteration suffices.
// After B1 everything is WAVE-LOCAL:
//   lane lam owns cols {256i + 4lam + e}: 4x ds_read_b128 (stride-16B,
//   conflict-free, 4KB/wave vs 16KB broadcast before), 64 FMAs with each
//   h value reused across the 4 gates, 24-op shfl_xor butterfly -> every
//   lane holds all 4 gate totals, all-lane-redundant gate math (no t<4
//   serialization), lane 0 publishes immediately. No B2, no lds_p.
// Deadlock-free: hbuf slot for epoch e is only overwritten at e+2, which
// requires all waves published e+1, which requires all waves consumed e
// (every wave is both producer and consumer). Same invariant as the
// previously harness-verified kernel.
template <typename XT>
__global__ __launch_bounds__(256, 1) void seq_kernel(
    const float* __restrict__ Whh,            // [4][4096][1024]
    const XT* __restrict__ XG,                // [epoch][k*16 + r*4 + q]
    float* __restrict__ hall,                 // [4096][1024]
    uint64_t* hbuf)                           // [2][1024]
{
    const int k = blockIdx.x;
    const int t = threadIdx.x;
    const int w = t >> 6;                     // wave id
    const int lam = t & 63;                   // lane id
    const int row = (k << 2) + w;             // hidden row owned by this wave

    // wreg[l][q][i*4+e] = Whh[l][q*1024+row][256*i + 4*lam + e]
    float wreg[4][4][16];
#pragma unroll
    for (int l = 0; l < 4; l++)
#pragma unroll
        for (int q = 0; q < 4; q++) {
            const float* src = Whh + ((size_t)l * H4 + q * 1024 + row) * 1024 + (lam << 2);
#pragma unroll
            for (int i = 0; i < 4; i++) {
                float4 v = *(const float4*)(src + (i << 8));
                wreg[l][q][i * 4 + 0] = v.x;
                wreg[l][q][i * 4 + 1] = v.y;
                wreg[l][q][i * 4 + 2] = v.z;
                wreg[l][q][i * 4 + 3] = v.w;
            }
        }

    __shared__ __align__(16) float lh[2][1024];   // epoch-parity double buffer
    float creg = 0.f;                             // c for this wave's row (all lanes)

    for (int step = 0; step < NS; ++step) {
#pragma unroll
        for (int l = 0; l < 4; l++) {
            const int it = step * 4 + l + 1;             // epoch being produced
            const uint32_t rtag = (uint32_t)(it - 1);
            uint64_t* rb = ((it - 1) & 1) ? (hbuf + 1024) : hbuf;
            uint64_t* wb = (it & 1) ? (hbuf + 1024) : hbuf;
            float* pb = lh[(it - 1) & 1];

            // ---- XG prefetch (wave-uniform address -> broadcast load),
            //      issued before polling so latency hides under the wait
            float xg0, xg1, xg2, xg3;
            {
                const XT* p = XG + (size_t)(it - 1) * H4 + (k << 4) + (w << 2);
                if constexpr (sizeof(XT) == 4) {
                    float4 v = *(const float4*)p;
                    xg0 = v.x; xg1 = v.y; xg2 = v.z; xg3 = v.w;
                } else {
                    ushort4 v = *(const ushort4*)p;
                    xg0 = __uint_as_float((uint32_t)v.x << 16);
                    xg1 = __uint_as_float((uint32_t)v.y << 16);
                    xg2 = __uint_as_float((uint32_t)v.z << 16);
                    xg3 = __uint_as_float((uint32_t)v.w << 16);
                }
            }

            // ---- cooperative poll + stage (thread t owns words t,256+t,512+t,768+t)
            uint32_t got = 0;
            while (got != 0xFu) {
#pragma unroll
                for (int m = 0; m < 4; m++) {
                    if (!(got & (1u << m))) {
                        uint64_t u = __hip_atomic_load(&rb[(m << 8) + t],
                                                       __ATOMIC_RELAXED, __HIP_MEMORY_SCOPE_AGENT);
                        if ((uint32_t)u == rtag) {
                            pb[(m << 8) + t] = __uint_as_float((uint32_t)(u >> 32));
                            got |= (1u << m);
                        }
                    }
                }
            }
            __syncthreads();   // B1: lh[parity] complete

            // ---- wave-local dot: all 4 gates of this wave's row
            float a0 = 0.f, a1 = 0.f, a2 = 0.f, a3 = 0.f;
#pragma unroll
            for (int i = 0; i < 4; i++) {
                const float4 hv = *(const float4*)(pb + (i << 8) + (lam << 2));
                a0 = fmaf(wreg[l][0][i * 4 + 0], hv.x, a0);
                a0 = fmaf(wreg[l][0][i * 4 + 1], hv.y, a0);
                a0 = fmaf(wreg[l][0][i * 4 + 2], hv.z, a0);
                a0 = fmaf(wreg[l][0][i * 4 + 3], hv.w, a0);
                a1 = fmaf(wreg[l][1][i * 4 + 0], hv.x, a1);
                a1 = fmaf(wreg[l][1][i * 4 + 1], hv.y, a1);
                a1 = fmaf(wreg[l][1][i * 4 + 2], hv.z, a1);
                a1 = fmaf(wreg[l][1][i * 4 + 3], hv.w, a1);
                a2 = fmaf(wreg[l][2][i * 4 + 0], hv.x, a2);
                a2 = fmaf(wreg[l][2][i * 4 + 1], hv.y, a2);
                a2 = fmaf(wreg[l][2][i * 4 + 2], hv.z, a2);
                a2 = fmaf(wreg[l][2][i * 4 + 3], hv.w, a2);
                a3 = fmaf(wreg[l][3][i * 4 + 0], hv.x, a3);
                a3 = fmaf(wreg[l][3][i * 4 + 1], hv.y, a3);
                a3 = fmaf(wreg[l][3][i * 4 + 2], hv.z, a3);
                a3 = fmaf(wreg[l][3][i * 4 + 3], hv.w, a3);
            }

            // ---- full butterfly: every lane ends with all 4 gate totals
#pragma unroll
            for (int s = 1; s < 64; s <<= 1) {
                a0 += __shfl_xor(a0, s);
                a1 += __shfl_xor(a1, s);
                a2 += __shfl_xor(a2, s);
                a3 += __shfl_xor(a3, s);
            }

            // ---- gates on all lanes (redundant, no divergence, no serialization)
            float gi = a0 + xg0, gf = a1 + xg1, gG = a2 + xg2, go = a3 + xg3;
            float cn = sigm_f(gf) * creg + sigm_f(gi) * tanh_f(gG);
            creg = cn;
            float hn = sigm_f(go) * tanh_f(cn);

            if (lam == 0) {
                if (l == 3) hall[(size_t)step * 1024 + row] = hn;
                uint64_t word = ((uint64_t)__float_as_uint(hn) << 32) | (uint64_t)(uint32_t)it;
                __hip_atomic_store(&wb[row], word,
                                   __ATOMIC_RELAXED, __HIP_MEMORY_SCOPE_AGENT);
            }
        }
    }
}

extern "C" void kernel_launch(void* const* d_in, const int* in_sizes, int n_in,
                              void* d_out, int out_size, void* d_ws, size_t ws_size,
                              hipStream_t stream)
{
    const float* x      = (const float*)d_in[0];
    const int*   ts     = (const int*)d_in[1];
    const float* proj_w = (const float*)d_in[2];
    const float* proj_b = (const float*)d_in[3];
    const float* te_w1  = (const float*)d_in[4];
    const float* te_b1  = (const float*)d_in[5];
    const float* te_w2  = (const float*)d_in[6];
    const float* te_b2  = (const float*)d_in[7];
    const float* Wih    = (const float*)d_in[8];
    const float* Whh    = (const float*)d_in[9];
    const float* bih    = (const float*)d_in[10];
    const float* bhh    = (const float*)d_in[11];
    const float* lin_w  = (const float*)d_in[12];
    const float* lin_b  = (const float*)d_in[13];
    float* out = (float*)d_out;

    char* ws = (char*)d_ws;
    const size_t MB16 = (size_t)NS * DT * 4;                    // 16 MiB
    float* bufA = (float*)ws;                                   // emb -> emb2 -> hall
    float* bufB = (float*)(ws + MB16);                          // h1 -> xp
    const size_t xg_f32_bytes  = (size_t)NS * 16384 * 4;        // 256 MiB
    const size_t xg_bf16_bytes = (size_t)NS * 16384 * 2;        // 128 MiB
    const bool use_f32_xg = ws_size >= 2 * MB16 + xg_f32_bytes + 16384 + 64;
    float*          XGf = (float*)(ws + 2 * MB16);
    __hip_bfloat16* XGb = (__hip_bfloat16*)(ws + 2 * MB16);
    uint64_t* hbuf = (uint64_t*)(ws + 2 * MB16 +
                                 (use_f32_xg ? xg_f32_bytes : xg_bf16_bytes));

    hipMemsetAsync(hbuf, 0, 2 * 1024 * sizeof(uint64_t), stream);

    // emb = sinusoidal(timesteps)
    emb_kernel<<<NS, 512, 0, stream>>>(ts, bufA);
    // h1 = silu(emb @ te_w1^T + te_b1)
    gemm_bt<true, false, 0><<<dim3(16, 32), 256, 0, stream>>>(
        bufA, te_w1, te_b1, nullptr, nullptr, bufB, nullptr, NS, DT, DT);
    // emb2 = h1 @ te_w2^T + te_b2
    gemm_bt<false, false, 0><<<dim3(16, 32), 256, 0, stream>>>(
        bufB, te_w2, te_b2, nullptr, nullptr, bufA, nullptr, NS, DT, DT);
    // xp = x @ proj_w^T + proj_b + emb2
    gemm_bt<false, true, 0><<<dim3(16, 32), 256, 0, stream>>>(
        x, proj_w, proj_b, nullptr, bufA, bufB, nullptr, NS, DT, DT);
    // XG[l] = xp @ Wih[l]^T + bih[l] + bhh[l]   (permuted layout), z = layer
    if (use_f32_xg) {
        gemm_bt<false, false, 2><<<dim3(64, 32, 4), 256, 0, stream>>>(
            bufB, Wih, bih, bhh, nullptr, XGf, nullptr, NS, H4, DT);
        seq_kernel<float><<<256, 256, 0, stream>>>(Whh, XGf, bufA, hbuf);
    } else {
        gemm_bt<false, false, 1><<<dim3(64, 32, 4), 256, 0, stream>>>(
            bufB, Wih, bih, bhh, nullptr, nullptr, XGb, NS, H4, DT);
        seq_kernel<__hip_bfloat16><<<256, 256, 0, stream>>>(Whh, XGb, bufA, hbuf);
    }
    // out = hall @ lin_w^T + lin_b
    gemm_bt<false, false, 0><<<dim3(16, 32), 256, 0, stream>>>(
        bufA, lin_w, lin_b, nullptr, nullptr, out, nullptr, NS, DT, DT);
}

// Round 3
// 51828.534 us; speedup vs baseline: 1.2457x; 1.2457x over previous
//
#include <hip/hip_runtime.h>
#include <hip/hip_bf16.h>
#include <stdint.h>

#define NS 4096     // samples / time steps
#define DT 1024     // dim_t == hidden == in
#define H4 4096     // 4*HID

// ---------- math helpers ----------
__device__ __forceinline__ float sigm_f(float x) { return 1.f / (1.f + __expf(-x)); }
__device__ __forceinline__ float tanh_f(float x) {
    float ax = fminf(fabsf(x), 15.f);                 // overflow-safe
    float t = 1.f - 2.f / (__expf(2.f * ax) + 1.f);
    return copysignf(t, x);
}

// ---------- sinusoidal embedding ----------
__global__ void emb_kernel(const int* __restrict__ ts, float* __restrict__ emb) {
    int t = blockIdx.x;
    int i = threadIdx.x;                 // 0..511
    float tv = (float)ts[t];
    const float c = -0.018024149455922082f;  // -ln(10000)/511
    float f = __expf(c * (float)i);
    float a = tv * f;
    float s, co;
    sincosf(a, &s, &co);
    emb[(size_t)t * DT + i] = s;
    emb[(size_t)t * DT + 512 + i] = co;
}

// ---------- generic C = A(M,K) @ B(Nc,K)^T + bias [+bias2] [+skip] [silu] ----------
// BM=128, BN=64, BK=16, 256 threads, each thread 8x4 outputs.
// XGMODE: 0 = plain fp32 C; 1 = bf16 XG layout; 2 = fp32 XG layout.
// XG layout per epoch (4096 elems): pos = k*16 + r*4 + q for col = q*1024 + 4k + r.
template <bool SILU, bool SKIP, int XGMODE>
__global__ __launch_bounds__(256) void gemm_bt(
    const float* __restrict__ A, const float* __restrict__ B,
    const float* __restrict__ bias, const float* __restrict__ bias2,
    const float* __restrict__ skip, float* __restrict__ Cf,
    __hip_bfloat16* __restrict__ Cb, int M, int Nc, int K)
{
    __shared__ __align__(16) float As[16][132];
    __shared__ __align__(16) float Bs[16][68];
    const int bn = blockIdx.x, bm = blockIdx.y, lz = blockIdx.z;
    if (XGMODE) {
        B     += (size_t)lz * H4 * DT;
        bias  += (size_t)lz * H4;
        bias2 += (size_t)lz * H4;
    }
    const int tid = threadIdx.x;
    const int tr = tid >> 4, tc = tid & 15;
    const int alr = tid >> 1, alc = (tid & 1) << 3;   // A: 128 rows x 16 cols
    const int blr = tid >> 2, blc = (tid & 3) << 2;   // B: 64 rows x 16 cols
    const float* Ap = A + (size_t)(bm * 128 + alr) * K + alc;
    const float* Bp = B + (size_t)(bn * 64 + blr) * K + blc;

    float acc[8][4];
#pragma unroll
    for (int i = 0; i < 8; i++)
#pragma unroll
        for (int j = 0; j < 4; j++) acc[i][j] = 0.f;

    for (int kk = 0; kk < K; kk += 16) {
        float4 a0 = *(const float4*)(Ap + kk);
        float4 a1 = *(const float4*)(Ap + kk + 4);
        float4 b0 = *(const float4*)(Bp + kk);
        __syncthreads();
        As[alc + 0][alr] = a0.x; As[alc + 1][alr] = a0.y;
        As[alc + 2][alr] = a0.z; As[alc + 3][alr] = a0.w;
        As[alc + 4][alr] = a1.x; As[alc + 5][alr] = a1.y;
        As[alc + 6][alr] = a1.z; As[alc + 7][alr] = a1.w;
        Bs[blc + 0][blr] = b0.x; Bs[blc + 1][blr] = b0.y;
        Bs[blc + 2][blr] = b0.z; Bs[blc + 3][blr] = b0.w;
        __syncthreads();
#pragma unroll
        for (int k = 0; k < 16; k++) {
            const float4 av0 = *(const float4*)&As[k][tr * 8];
            const float4 av1 = *(const float4*)&As[k][tr * 8 + 4];
            const float4 bv  = *(const float4*)&Bs[k][tc * 4];
            float aa[8] = {av0.x, av0.y, av0.z, av0.w, av1.x, av1.y, av1.z, av1.w};
            float bb[4] = {bv.x, bv.y, bv.z, bv.w};
#pragma unroll
            for (int i = 0; i < 8; i++)
#pragma unroll
                for (int j = 0; j < 4; j++)
                    acc[i][j] = fmaf(aa[i], bb[j], acc[i][j]);
        }
    }

#pragma unroll
    for (int i = 0; i < 8; i++) {
        int row = bm * 128 + tr * 8 + i;
#pragma unroll
        for (int j = 0; j < 4; j++) {
            int col = bn * 64 + tc * 4 + j;
            float v = acc[i][j] + bias[col];
            if (XGMODE) v += bias2[col];
            if (SKIP)   v += skip[(size_t)row * Nc + col];
            if (SILU)   v = v * (1.f / (1.f + __expf(-v)));
            if (XGMODE) {
                int q = col >> 10, jj = col & 1023;
                size_t idx = (size_t)row * 16384 + (size_t)lz * 4096
                           + ((size_t)(jj >> 2) << 4) + ((jj & 3) << 2) + q;
                if (XGMODE == 2) Cf[idx] = v;
                else             Cb[idx] = __float2bfloat16(v);
            } else {
                Cf[(size_t)row * Nc + col] = v;
            }
        }
    }
}

// ---------- persistent sequential LSTM chain ----------
// 256 WGs x 256 threads (1 block/CU). Wave-owns-row: wave w of WG k owns
// hidden row 4k+w and computes all 4 gates of that row.
//   - cooperative poll+stage into epoch-parity LDS buffer (B1 = sole barrier)
//   - wave-local dot: lane lam owns cols {256i+4lam+e}; 4x conflict-free
//     ds_read_b128, 64 FMAs with 4x h-reuse (verified round 2: bank
//     conflicts 1.7e7 -> 0)
//   - 24-op shfl_xor butterfly -> all lanes hold the 4 gate sums; gate math
//     all-lane redundant (no serialized tail)
// PUBLISH (round-2 post-mortem fix): per-wave lane-0 8B agent stores caused
// 4x WRITE_SIZE (557 MB vs 164 MB) + serialized line-ownership ping-pong on
// the critical path. Restore the round-0 coalesced pattern via LDS mailbox:
// lane 0 of wave w deposits (h,tag) in mbox[w]; lanes 0-3 of wave 0 spin on
// the mailbox (no extra barrier) and issue ONE coalesced 4xu64 = 32B agent
// store + coalesced 16B hall write.
// Mailbox safety: mbox[w]@e+1 is written only after wave w passed its poll
// of epoch e, which requires all WGs published e, which requires wave 0
// consumed mbox[w]@e. Tags strictly increase; slots zeroed before first B1.
// hbuf parity safety: slot for epoch e overwritten only at e+2 (unchanged
// invariant from the harness-verified round-0 kernel).
template <typename XT>
__global__ __launch_bounds__(256, 1) void seq_kernel(
    const float* __restrict__ Whh,            // [4][4096][1024]
    const XT* __restrict__ XG,                // [epoch][k*16 + r*4 + q]
    float* __restrict__ hall,                 // [4096][1024]
    uint64_t* hbuf)                           // [2][1024]
{
    const int k = blockIdx.x;
    const int t = threadIdx.x;
    const int w = t >> 6;                     // wave id
    const int lam = t & 63;                   // lane id
    const int row = (k << 2) + w;             // hidden row owned by this wave

    // wreg[l][q][i*4+e] = Whh[l][q*1024+row][256*i + 4*lam + e]
    float wreg[4][4][16];
#pragma unroll
    for (int l = 0; l < 4; l++)
#pragma unroll
        for (int q = 0; q < 4; q++) {
            const float* src = Whh + ((size_t)l * H4 + q * 1024 + row) * 1024 + (lam << 2);
#pragma unroll
            for (int i = 0; i < 4; i++) {
                float4 v = *(const float4*)(src + (i << 8));
                wreg[l][q][i * 4 + 0] = v.x;
                wreg[l][q][i * 4 + 1] = v.y;
                wreg[l][q][i * 4 + 2] = v.z;
                wreg[l][q][i * 4 + 3] = v.w;
            }
        }

    __shared__ __align__(16) float lh[2][1024];   // epoch-parity double buffer
    __shared__ __align__(8) uint64_t mbox[4];     // per-wave publish mailbox
    if (t < 4) mbox[t] = 0;                       // ordered by first B1
    float creg = 0.f;                             // c for this wave's row (all lanes)

    for (int step = 0; step < NS; ++step) {
#pragma unroll
        for (int l = 0; l < 4; l++) {
            const int it = step * 4 + l + 1;             // epoch being produced
            const uint32_t rtag = (uint32_t)(it - 1);
            uint64_t* rb = ((it - 1) & 1) ? (hbuf + 1024) : hbuf;
            uint64_t* wb = (it & 1) ? (hbuf + 1024) : hbuf;
            float* pb = lh[(it - 1) & 1];

            // ---- XG prefetch (wave-uniform address -> broadcast load),
            //      issued before polling so latency hides under the wait
            float xg0, xg1, xg2, xg3;
            {
                const XT* p = XG + (size_t)(it - 1) * H4 + (k << 4) + (w << 2);
                if constexpr (sizeof(XT) == 4) {
                    float4 v = *(const float4*)p;
                    xg0 = v.x; xg1 = v.y; xg2 = v.z; xg3 = v.w;
                } else {
                    ushort4 v = *(const ushort4*)p;
                    xg0 = __uint_as_float((uint32_t)v.x << 16);
                    xg1 = __uint_as_float((uint32_t)v.y << 16);
                    xg2 = __uint_as_float((uint32_t)v.z << 16);
                    xg3 = __uint_as_float((uint32_t)v.w << 16);
                }
            }

            // ---- cooperative poll + stage (thread t owns words t,256+t,512+t,768+t)
            uint32_t got = 0;
            while (got != 0xFu) {
#pragma unroll
                for (int m = 0; m < 4; m++) {
                    if (!(got & (1u << m))) {
                        uint64_t u = __hip_atomic_load(&rb[(m << 8) + t],
                                                       __ATOMIC_RELAXED, __HIP_MEMORY_SCOPE_AGENT);
                        if ((uint32_t)u == rtag) {
                            pb[(m << 8) + t] = __uint_as_float((uint32_t)(u >> 32));
                            got |= (1u << m);
                        }
                    }
                }
            }
            __syncthreads();   // B1: lh[parity] complete (also orders mbox init/reuse)

            // ---- wave-local dot: all 4 gates of this wave's row
            float a0 = 0.f, a1 = 0.f, a2 = 0.f, a3 = 0.f;
#pragma unroll
            for (int i = 0; i < 4; i++) {
                const float4 hv = *(const float4*)(pb + (i << 8) + (lam << 2));
                a0 = fmaf(wreg[l][0][i * 4 + 0], hv.x, a0);
                a0 = fmaf(wreg[l][0][i * 4 + 1], hv.y, a0);
                a0 = fmaf(wreg[l][0][i * 4 + 2], hv.z, a0);
                a0 = fmaf(wreg[l][0][i * 4 + 3], hv.w, a0);
                a1 = fmaf(wreg[l][1][i * 4 + 0], hv.x, a1);
                a1 = fmaf(wreg[l][1][i * 4 + 1], hv.y, a1);
                a1 = fmaf(wreg[l][1][i * 4 + 2], hv.z, a1);
                a1 = fmaf(wreg[l][1][i * 4 + 3], hv.w, a1);
                a2 = fmaf(wreg[l][2][i * 4 + 0], hv.x, a2);
                a2 = fmaf(wreg[l][2][i * 4 + 1], hv.y, a2);
                a2 = fmaf(wreg[l][2][i * 4 + 2], hv.z, a2);
                a2 = fmaf(wreg[l][2][i * 4 + 3], hv.w, a2);
                a3 = fmaf(wreg[l][3][i * 4 + 0], hv.x, a3);
                a3 = fmaf(wreg[l][3][i * 4 + 1], hv.y, a3);
                a3 = fmaf(wreg[l][3][i * 4 + 2], hv.z, a3);
                a3 = fmaf(wreg[l][3][i * 4 + 3], hv.w, a3);
            }

            // ---- full butterfly: every lane ends with all 4 gate totals
#pragma unroll
            for (int s = 1; s < 64; s <<= 1) {
                a0 += __shfl_xor(a0, s);
                a1 += __shfl_xor(a1, s);
                a2 += __shfl_xor(a2, s);
                a3 += __shfl_xor(a3, s);
            }

            // ---- gates on all lanes (redundant, no divergence)
            float gi = a0 + xg0, gf = a1 + xg1, gG = a2 + xg2, go = a3 + xg3;
            float cn = sigm_f(gf) * creg + sigm_f(gi) * tanh_f(gG);
            creg = cn;
            float hn = sigm_f(go) * tanh_f(cn);

            // ---- deposit in mailbox (per-wave lane 0)
            if (lam == 0) {
                uint64_t word = ((uint64_t)__float_as_uint(hn) << 32) | (uint64_t)(uint32_t)it;
                __hip_atomic_store(&mbox[w], word,
                                   __ATOMIC_RELAXED, __HIP_MEMORY_SCOPE_WORKGROUP);
            }

            // ---- wave 0 gathers + single coalesced 32B agent publish
            if (t < 4) {
                uint64_t u;
                do {
                    u = __hip_atomic_load(&mbox[t],
                                          __ATOMIC_RELAXED, __HIP_MEMORY_SCOPE_WORKGROUP);
                } while ((uint32_t)u != (uint32_t)it);
                if (l == 3)
                    hall[(size_t)step * 1024 + (k << 2) + t] =
                        __uint_as_float((uint32_t)(u >> 32));
                __hip_atomic_store(&wb[(k << 2) + t], u,
                                   __ATOMIC_RELAXED, __HIP_MEMORY_SCOPE_AGENT);
            }
        }
    }
}

extern "C" void kernel_launch(void* const* d_in, const int* in_sizes, int n_in,
                              void* d_out, int out_size, void* d_ws, size_t ws_size,
                              hipStream_t stream)
{
    const float* x      = (const float*)d_in[0];
    const int*   ts     = (const int*)d_in[1];
    const float* proj_w = (const float*)d_in[2];
    const float* proj_b = (const float*)d_in[3];
    const float* te_w1  = (const float*)d_in[4];
    const float* te_b1  = (const float*)d_in[5];
    const float* te_w2  = (const float*)d_in[6];
    const float* te_b2  = (const float*)d_in[7];
    const float* Wih    = (const float*)d_in[8];
    const float* Whh    = (const float*)d_in[9];
    const float* bih    = (const float*)d_in[10];
    const float* bhh    = (const float*)d_in[11];
    const float* lin_w  = (const float*)d_in[12];
    const float* lin_b  = (const float*)d_in[13];
    float* out = (float*)d_out;

    char* ws = (char*)d_ws;
    const size_t MB16 = (size_t)NS * DT * 4;                    // 16 MiB
    float* bufA = (float*)ws;                                   // emb -> emb2 -> hall
    float* bufB = (float*)(ws + MB16);                          // h1 -> xp
    const size_t xg_f32_bytes  = (size_t)NS * 16384 * 4;        // 256 MiB
    const size_t xg_bf16_bytes = (size_t)NS * 16384 * 2;        // 128 MiB
    const bool use_f32_xg = ws_size >= 2 * MB16 + xg_f32_bytes + 16384 + 64;
    float*          XGf = (float*)(ws + 2 * MB16);
    __hip_bfloat16* XGb = (__hip_bfloat16*)(ws + 2 * MB16);
    uint64_t* hbuf = (uint64_t*)(ws + 2 * MB16 +
                                 (use_f32_xg ? xg_f32_bytes : xg_bf16_bytes));

    hipMemsetAsync(hbuf, 0, 2 * 1024 * sizeof(uint64_t), stream);

    // emb = sinusoidal(timesteps)
    emb_kernel<<<NS, 512, 0, stream>>>(ts, bufA);
    // h1 = silu(emb @ te_w1^T + te_b1)
    gemm_bt<true, false, 0><<<dim3(16, 32), 256, 0, stream>>>(
        bufA, te_w1, te_b1, nullptr, nullptr, bufB, nullptr, NS, DT, DT);
    // emb2 = h1 @ te_w2^T + te_b2
    gemm_bt<false, false, 0><<<dim3(16, 32), 256, 0, stream>>>(
        bufB, te_w2, te_b2, nullptr, nullptr, bufA, nullptr, NS, DT, DT);
    // xp = x @ proj_w^T + proj_b + emb2
    gemm_bt<false, true, 0><<<dim3(16, 32), 256, 0, stream>>>(
        x, proj_w, proj_b, nullptr, bufA, bufB, nullptr, NS, DT, DT);
    // XG[l] = xp @ Wih[l]^T + bih[l] + bhh[l]   (permuted layout), z = layer
    if (use_f32_xg) {
        gemm_bt<false, false, 2><<<dim3(64, 32, 4), 256, 0, stream>>>(
            bufB, Wih, bih, bhh, nullptr, XGf, nullptr, NS, H4, DT);
        seq_kernel<float><<<256, 256, 0, stream>>>(Whh, XGf, bufA, hbuf);
    } else {
        gemm_bt<false, false, 1><<<dim3(64, 32, 4), 256, 0, stream>>>(
            bufB, Wih, bih, bhh, nullptr, nullptr, XGb, NS, H4, DT);
        seq_kernel<__hip_bfloat16><<<256, 256, 0, stream>>>(Whh, XGb, bufA, hbuf);
    }
    // out = hall @ lin_w^T + lin_b
    gemm_bt<false, false, 0><<<dim3(16, 32), 256, 0, stream>>>(
        bufA, lin_w, lin_b, nullptr, nullptr, out, nullptr, NS, DT, DT);
}

// Round 5
// 48349.606 us; speedup vs baseline: 1.3354x; 1.0720x over previous
//
#include <hip/hip_runtime.h>
#include <hip/hip_bf16.h>
#include <stdint.h>

#define NS 4096     // samples / time steps
#define DT 1024     // dim_t == hidden == in
#define H4 4096     // 4*HID

// ---------- math helpers ----------
__device__ __forceinline__ float sigm_f(float x) { return 1.f / (1.f + __expf(-x)); }
__device__ __forceinline__ float tanh_f(float x) {
    float ax = fminf(fabsf(x), 15.f);                 // overflow-safe
    float t = 1.f - 2.f / (__expf(2.f * ax) + 1.f);
    return copysignf(t, x);
}

// ---------- sinusoidal embedding ----------
__global__ void emb_kernel(const int* __restrict__ ts, float* __restrict__ emb) {
    int t = blockIdx.x;
    int i = threadIdx.x;                 // 0..511
    float tv = (float)ts[t];
    const float c = -0.018024149455922082f;  // -ln(10000)/511
    float f = __expf(c * (float)i);
    float a = tv * f;
    float s, co;
    sincosf(a, &s, &co);
    emb[(size_t)t * DT + i] = s;
    emb[(size_t)t * DT + 512 + i] = co;
}

// ---------- generic C = A(M,K) @ B(Nc,K)^T + bias [+bias2] [+skip] [silu] ----------
// BM=128, BN=64, BK=16, 256 threads, each thread 8x4 outputs.
// XGMODE: 0 = plain fp32 C; 1 = bf16 XG layout; 2 = fp32 XG layout.
// XG layout per epoch (4096 elems): pos = k*16 + r*4 + q for col = q*1024 + 4k + r.
template <bool SILU, bool SKIP, int XGMODE>
__global__ __launch_bounds__(256) void gemm_bt(
    const float* __restrict__ A, const float* __restrict__ B,
    const float* __restrict__ bias, const float* __restrict__ bias2,
    const float* __restrict__ skip, float* __restrict__ Cf,
    __hip_bfloat16* __restrict__ Cb, int M, int Nc, int K)
{
    __shared__ __align__(16) float As[16][132];
    __shared__ __align__(16) float Bs[16][68];
    const int bn = blockIdx.x, bm = blockIdx.y, lz = blockIdx.z;
    if (XGMODE) {
        B     += (size_t)lz * H4 * DT;
        bias  += (size_t)lz * H4;
        bias2 += (size_t)lz * H4;
    }
    const int tid = threadIdx.x;
    const int tr = tid >> 4, tc = tid & 15;
    const int alr = tid >> 1, alc = (tid & 1) << 3;   // A: 128 rows x 16 cols
    const int blr = tid >> 2, blc = (tid & 3) << 2;   // B: 64 rows x 16 cols
    const float* Ap = A + (size_t)(bm * 128 + alr) * K + alc;
    const float* Bp = B + (size_t)(bn * 64 + blr) * K + blc;

    float acc[8][4];
#pragma unroll
    for (int i = 0; i < 8; i++)
#pragma unroll
        for (int j = 0; j < 4; j++) acc[i][j] = 0.f;

    for (int kk = 0; kk < K; kk += 16) {
        float4 a0 = *(const float4*)(Ap + kk);
        float4 a1 = *(const float4*)(Ap + kk + 4);
        float4 b0 = *(const float4*)(Bp + kk);
        __syncthreads();
        As[alc + 0][alr] = a0.x; As[alc + 1][alr] = a0.y;
        As[alc + 2][alr] = a0.z; As[alc + 3][alr] = a0.w;
        As[alc + 4][alr] = a1.x; As[alc + 5][alr] = a1.y;
        As[alc + 6][alr] = a1.z; As[alc + 7][alr] = a1.w;
        Bs[blc + 0][blr] = b0.x; Bs[blc + 1][blr] = b0.y;
        Bs[blc + 2][blr] = b0.z; Bs[blc + 3][blr] = b0.w;
        __syncthreads();
#pragma unroll
        for (int k = 0; k < 16; k++) {
            const float4 av0 = *(const float4*)&As[k][tr * 8];
            const float4 av1 = *(const float4*)&As[k][tr * 8 + 4];
            const float4 bv  = *(const float4*)&Bs[k][tc * 4];
            float aa[8] = {av0.x, av0.y, av0.z, av0.w, av1.x, av1.y, av1.z, av1.w};
            float bb[4] = {bv.x, bv.y, bv.z, bv.w};
#pragma unroll
            for (int i = 0; i < 8; i++)
#pragma unroll
                for (int j = 0; j < 4; j++)
                    acc[i][j] = fmaf(aa[i], bb[j], acc[i][j]);
        }
    }

#pragma unroll
    for (int i = 0; i < 8; i++) {
        int row = bm * 128 + tr * 8 + i;
#pragma unroll
        for (int j = 0; j < 4; j++) {
            int col = bn * 64 + tc * 4 + j;
            float v = acc[i][j] + bias[col];
            if (XGMODE) v += bias2[col];
            if (SKIP)   v += skip[(size_t)row * Nc + col];
            if (SILU)   v = v * (1.f / (1.f + __expf(-v)));
            if (XGMODE) {
                int q = col >> 10, jj = col & 1023;
                size_t idx = (size_t)row * 16384 + (size_t)lz * 4096
                           + ((size_t)(jj >> 2) << 4) + ((jj & 3) << 2) + q;
                if (XGMODE == 2) Cf[idx] = v;
                else             Cb[idx] = __float2bfloat16(v);
            } else {
                Cf[(size_t)row * Nc + col] = v;
            }
        }
    }
}

// ---------- persistent sequential LSTM chain ----------
// 256 WGs x 256 threads (1 block/CU). Wave-owns-row: wave w of WG k owns
// hidden row 4k+w and computes all 4 gates of that row.
// Evidence trail:
//   r2: wave-local dot killed bank conflicts (1.7e7 -> 0) but per-wave 8B
//       publishes 4x'd WRITE_SIZE -> regression.
//   r3: LDS-mailbox coalesced publish restored WRITE_SIZE (557MB -> 164MB,
//       predicted) but dur still 47ms: (a) 24-op butterfly x4 waves = 96
//       DS ops/CU/epoch on the shared LDS pipe; (b) poll storm: each WG
//       re-reads the 8KB hbuf ~10x/epoch => ~20MB/epoch chip-wide ~ 8TB/s
//       -> coherent-fabric congestion sets the epoch period.
// r4 fixes (resubmitted unchanged after infra-only failure):
//   (1) s_sleep(8) backoff after each failed poll scan: ~3-4x fewer poll
//       iterations -> fabric below saturation. Protocol unchanged (finite
//       sleep, re-poll) => no deadlock surface.
//   (2) accumulator-fold reduction: 3 shfl fold (4 accs -> 1 per lane,
//       gate q=lam&3), 4-stage group butterfly, 3 shfl redistribute +
//       12 cndmask => 10 DS ops vs 24 (case-verified over all q).
// Publish: lane 0 of wave w deposits (h,tag) in mbox[w]; lanes 0-3 of wave
// 0 spin on the mailbox and issue ONE coalesced 4xu64 = 32B agent store +
// coalesced 16B hall write.
// Mailbox safety: mbox[w]@e+1 written only after wave w passed its poll of
// epoch e, which requires all WGs published e, which requires wave 0
// consumed mbox[w]@e. Tags strictly increase; slots zeroed before first B1.
// hbuf parity safety: slot for epoch e overwritten only at e+2 (invariant
// inherited from the harness-verified round-0 kernel).
template <typename XT>
__global__ __launch_bounds__(256, 1) void seq_kernel(
    const float* __restrict__ Whh,            // [4][4096][1024]
    const XT* __restrict__ XG,                // [epoch][k*16 + r*4 + q]
    float* __restrict__ hall,                 // [4096][1024]
    uint64_t* hbuf)                           // [2][1024]
{
    const int k = blockIdx.x;
    const int t = threadIdx.x;
    const int w = t >> 6;                     // wave id
    const int lam = t & 63;                   // lane id
    const int row = (k << 2) + w;             // hidden row owned by this wave

    // wreg[l][q][i*4+e] = Whh[l][q*1024+row][256*i + 4*lam + e]
    float wreg[4][4][16];
#pragma unroll
    for (int l = 0; l < 4; l++)
#pragma unroll
        for (int q = 0; q < 4; q++) {
            const float* src = Whh + ((size_t)l * H4 + q * 1024 + row) * 1024 + (lam << 2);
#pragma unroll
            for (int i = 0; i < 4; i++) {
                float4 v = *(const float4*)(src + (i << 8));
                wreg[l][q][i * 4 + 0] = v.x;
                wreg[l][q][i * 4 + 1] = v.y;
                wreg[l][q][i * 4 + 2] = v.z;
                wreg[l][q][i * 4 + 3] = v.w;
            }
        }

    __shared__ __align__(16) float lh[2][1024];   // epoch-parity double buffer
    __shared__ __align__(8) uint64_t mbox[4];     // per-wave publish mailbox
    if (t < 4) mbox[t] = 0;                       // ordered by first B1
    float creg = 0.f;                             // c for this wave's row (all lanes)

    const bool b1 = (lam & 1) != 0, b2 = (lam & 2) != 0;

    for (int step = 0; step < NS; ++step) {
#pragma unroll
        for (int l = 0; l < 4; l++) {
            const int it = step * 4 + l + 1;             // epoch being produced
            const uint32_t rtag = (uint32_t)(it - 1);
            uint64_t* rb = ((it - 1) & 1) ? (hbuf + 1024) : hbuf;
            uint64_t* wb = (it & 1) ? (hbuf + 1024) : hbuf;
            float* pb = lh[(it - 1) & 1];

            // ---- XG prefetch (wave-uniform address -> broadcast load),
            //      issued before polling so latency hides under the wait
            float xg0, xg1, xg2, xg3;
            {
                const XT* p = XG + (size_t)(it - 1) * H4 + (k << 4) + (w << 2);
                if constexpr (sizeof(XT) == 4) {
                    float4 v = *(const float4*)p;
                    xg0 = v.x; xg1 = v.y; xg2 = v.z; xg3 = v.w;
                } else {
                    ushort4 v = *(const ushort4*)p;
                    xg0 = __uint_as_float((uint32_t)v.x << 16);
                    xg1 = __uint_as_float((uint32_t)v.y << 16);
                    xg2 = __uint_as_float((uint32_t)v.z << 16);
                    xg3 = __uint_as_float((uint32_t)v.w << 16);
                }
            }

            // ---- cooperative poll + stage (thread t owns words t,256+t,512+t,768+t)
            //      with s_sleep backoff to keep the poll storm off the fabric
            uint32_t got = 0;
            while (got != 0xFu) {
#pragma unroll
                for (int m = 0; m < 4; m++) {
                    if (!(got & (1u << m))) {
                        uint64_t u = __hip_atomic_load(&rb[(m << 8) + t],
                                                       __ATOMIC_RELAXED, __HIP_MEMORY_SCOPE_AGENT);
                        if ((uint32_t)u == rtag) {
                            pb[(m << 8) + t] = __uint_as_float((uint32_t)(u >> 32));
                            got |= (1u << m);
                        }
                    }
                }
                if (got != 0xFu) __builtin_amdgcn_s_sleep(8);   // ~512 cy backoff
            }
            __syncthreads();   // B1: lh[parity] complete (also orders mbox init/reuse)

            // ---- wave-local dot: all 4 gates of this wave's row
            float a0 = 0.f, a1 = 0.f, a2 = 0.f, a3 = 0.f;
#pragma unroll
            for (int i = 0; i < 4; i++) {
                const float4 hv = *(const float4*)(pb + (i << 8) + (lam << 2));
                a0 = fmaf(wreg[l][0][i * 4 + 0], hv.x, a0);
                a0 = fmaf(wreg[l][0][i * 4 + 1], hv.y, a0);
                a0 = fmaf(wreg[l][0][i * 4 + 2], hv.z, a0);
                a0 = fmaf(wreg[l][0][i * 4 + 3], hv.w, a0);
                a1 = fmaf(wreg[l][1][i * 4 + 0], hv.x, a1);
                a1 = fmaf(wreg[l][1][i * 4 + 1], hv.y, a1);
                a1 = fmaf(wreg[l][1][i * 4 + 2], hv.z, a1);
                a1 = fmaf(wreg[l][1][i * 4 + 3], hv.w, a1);
                a2 = fmaf(wreg[l][2][i * 4 + 0], hv.x, a2);
                a2 = fmaf(wreg[l][2][i * 4 + 1], hv.y, a2);
                a2 = fmaf(wreg[l][2][i * 4 + 2], hv.z, a2);
                a2 = fmaf(wreg[l][2][i * 4 + 3], hv.w, a2);
                a3 = fmaf(wreg[l][3][i * 4 + 0], hv.x, a3);
                a3 = fmaf(wreg[l][3][i * 4 + 1], hv.y, a3);
                a3 = fmaf(wreg[l][3][i * 4 + 2], hv.z, a3);
                a3 = fmaf(wreg[l][3][i * 4 + 3], hv.w, a3);
            }

            // ---- fold reduction: 10 DS ops total (r3 post-mortem: 24-op
            //      butterfly x4 waves contended the shared LDS pipe).
            // Fold 4 accs into lane space (lane ends with gate q=lam&3's
            // 4-lane-group sum), butterfly over groups, redistribute.
            {
                float x  = __shfl_xor(b1 ? a0 : a1, 1);
                float y  = __shfl_xor(b1 ? a2 : a3, 1);
                float na = (b1 ? a1 : a0) + x;
                float nb = (b1 ? a3 : a2) + y;
                float z  = __shfl_xor(b2 ? na : nb, 2);
                float nc = (b2 ? nb : na) + z;
                nc += __shfl_xor(nc, 4);
                nc += __shfl_xor(nc, 8);
                nc += __shfl_xor(nc, 16);
                nc += __shfl_xor(nc, 32);
                float g1 = __shfl_xor(nc, 1);       // gate q^1
                float g2 = __shfl_xor(nc, 2);       // gate q^2
                float g3 = __shfl_xor(g1, 2);       // gate q^3
                // variable m holds gate q^m; gate j lives at index j^q
                a0 = b1 ? (b2 ? g3 : g1) : (b2 ? g2 : nc);   // gate 0 (i)
                a1 = b1 ? (b2 ? g2 : nc) : (b2 ? g3 : g1);   // gate 1 (f)
                a2 = b1 ? (b2 ? g1 : g3) : (b2 ? nc : g2);   // gate 2 (g)
                a3 = b1 ? (b2 ? nc : g2) : (b2 ? g1 : g3);   // gate 3 (o)
            }

            // ---- gates on all lanes (redundant, no divergence)
            float gi = a0 + xg0, gf = a1 + xg1, gG = a2 + xg2, go = a3 + xg3;
            float cn = sigm_f(gf) * creg + sigm_f(gi) * tanh_f(gG);
            creg = cn;
            float hn = sigm_f(go) * tanh_f(cn);

            // ---- deposit in mailbox (per-wave lane 0)
            if (lam == 0) {
                uint64_t word = ((uint64_t)__float_as_uint(hn) << 32) | (uint64_t)(uint32_t)it;
                __hip_atomic_store(&mbox[w], word,
                                   __ATOMIC_RELAXED, __HIP_MEMORY_SCOPE_WORKGROUP);
            }

            // ---- wave 0 gathers + single coalesced 32B agent publish
            if (t < 4) {
                uint64_t u;
                do {
                    u = __hip_atomic_load(&mbox[t],
                                          __ATOMIC_RELAXED, __HIP_MEMORY_SCOPE_WORKGROUP);
                } while ((uint32_t)u != (uint32_t)it);
                if (l == 3)
                    hall[(size_t)step * 1024 + (k << 2) + t] =
                        __uint_as_float((uint32_t)(u >> 32));
                __hip_atomic_store(&wb[(k << 2) + t], u,
                                   __ATOMIC_RELAXED, __HIP_MEMORY_SCOPE_AGENT);
            }
        }
    }
}

extern "C" void kernel_launch(void* const* d_in, const int* in_sizes, int n_in,
                              void* d_out, int out_size, void* d_ws, size_t ws_size,
                              hipStream_t stream)
{
    const float* x      = (const float*)d_in[0];
    const int*   ts     = (const int*)d_in[1];
    const float* proj_w = (const float*)d_in[2];
    const float* proj_b = (const float*)d_in[3];
    const float* te_w1  = (const float*)d_in[4];
    const float* te_b1  = (const float*)d_in[5];
    const float* te_w2  = (const float*)d_in[6];
    const float* te_b2  = (const float*)d_in[7];
    const float* Wih    = (const float*)d_in[8];
    const float* Whh    = (const float*)d_in[9];
    const float* bih    = (const float*)d_in[10];
    const float* bhh    = (const float*)d_in[11];
    const float* lin_w  = (const float*)d_in[12];
    const float* lin_b  = (const float*)d_in[13];
    float* out = (float*)d_out;

    char* ws = (char*)d_ws;
    const size_t MB16 = (size_t)NS * DT * 4;                    // 16 MiB
    float* bufA = (float*)ws;                                   // emb -> emb2 -> hall
    float* bufB = (float*)(ws + MB16);                          // h1 -> xp
    const size_t xg_f32_bytes  = (size_t)NS * 16384 * 4;        // 256 MiB
    const size_t xg_bf16_bytes = (size_t)NS * 16384 * 2;        // 128 MiB
    const bool use_f32_xg = ws_size >= 2 * MB16 + xg_f32_bytes + 16384 + 64;
    float*          XGf = (float*)(ws + 2 * MB16);
    __hip_bfloat16* XGb = (__hip_bfloat16*)(ws + 2 * MB16);
    uint64_t* hbuf = (uint64_t*)(ws + 2 * MB16 +
                                 (use_f32_xg ? xg_f32_bytes : xg_bf16_bytes));

    hipMemsetAsync(hbuf, 0, 2 * 1024 * sizeof(uint64_t), stream);

    // emb = sinusoidal(timesteps)
    emb_kernel<<<NS, 512, 0, stream>>>(ts, bufA);
    // h1 = silu(emb @ te_w1^T + te_b1)
    gemm_bt<true, false, 0><<<dim3(16, 32), 256, 0, stream>>>(
        bufA, te_w1, te_b1, nullptr, nullptr, bufB, nullptr, NS, DT, DT);
    // emb2 = h1 @ te_w2^T + te_b2
    gemm_bt<false, false, 0><<<dim3(16, 32), 256, 0, stream>>>(
        bufB, te_w2, te_b2, nullptr, nullptr, bufA, nullptr, NS, DT, DT);
    // xp = x @ proj_w^T + proj_b + emb2
    gemm_bt<false, true, 0><<<dim3(16, 32), 256, 0, stream>>>(
        x, proj_w, proj_b, nullptr, bufA, bufB, nullptr, NS, DT, DT);
    // XG[l] = xp @ Wih[l]^T + bih[l] + bhh[l]   (permuted layout), z = layer
    if (use_f32_xg) {
        gemm_bt<false, false, 2><<<dim3(64, 32, 4), 256, 0, stream>>>(
            bufB, Wih, bih, bhh, nullptr, XGf, nullptr, NS, H4, DT);
        seq_kernel<float><<<256, 256, 0, stream>>>(Whh, XGf, bufA, hbuf);
    } else {
        gemm_bt<false, false, 1><<<dim3(64, 32, 4), 256, 0, stream>>>(
            bufB, Wih, bih, bhh, nullptr, nullptr, XGb, NS, H4, DT);
        seq_kernel<__hip_bfloat16><<<256, 256, 0, stream>>>(Whh, XGb, bufA, hbuf);
    }
    // out = hall @ lin_w^T + lin_b
    gemm_bt<false, false, 0><<<dim3(16, 32), 256, 0, stream>>>(
        bufA, lin_w, lin_b, nullptr, nullptr, out, nullptr, NS, DT, DT);
}